// Round 1
// 4631.226 us; speedup vs baseline: 1.4499x; 1.4499x over previous
//
#include <hip/hip_runtime.h>
#include <cstddef>
#include <cstdint>

#define NNODE 20000
#define NEDGE 320000
#define NFEDGE 500000
#define DIM 256
#define NHEAD 8
#define NGRAPH 100
// 1/sqrt(32)
#define INV_SCALE 0.17677669529663687f

typedef _Float16 f16x8 __attribute__((ext_vector_type(8)));
typedef float f32x4 __attribute__((ext_vector_type(4)));

// ---------------------------------------------------------------------------
// Generic fp32 GEMM: C = A(MxK) @ W(KxNn) + bias (+ res). 64x64 tile, BK=16,
// 256 threads, 4x4 microtile per thread.  (unchanged this round)
// ---------------------------------------------------------------------------
__global__ __launch_bounds__(256)
void gemm_kernel(const float* __restrict__ A, const float* __restrict__ W,
                 const float* __restrict__ bias, const float* __restrict__ res,
                 float* __restrict__ C, int M, int K, int Nn)
{
    __shared__ float As[16][64];
    __shared__ float Ws[16][64];
    const int tid = threadIdx.x;
    const int tx = tid & 15;         // N direction (x4)
    const int ty = tid >> 4;         // M direction (x4)
    const int m0 = blockIdx.y * 64;
    const int n0 = blockIdx.x * 64;

    float c[4][4] = {};

    for (int k0 = 0; k0 < K; k0 += 16) {
        {
            int r  = tid >> 2;
            int k4 = (tid & 3) * 4;
            int row = m0 + r; if (row >= M) row = M - 1;
            const float4 v = *(const float4*)(A + (size_t)row * K + k0 + k4);
            As[k4 + 0][r] = v.x; As[k4 + 1][r] = v.y;
            As[k4 + 2][r] = v.z; As[k4 + 3][r] = v.w;
        }
        {
            int kr = tid >> 4;
            int n4 = (tid & 15) * 4;
            *(float4*)&Ws[kr][n4] = *(const float4*)(W + (size_t)(k0 + kr) * Nn + n0 + n4);
        }
        __syncthreads();
        #pragma unroll
        for (int kk = 0; kk < 16; ++kk) {
            float a_[4], w_[4];
            *(float4*)a_ = *(const float4*)&As[kk][ty * 4];
            *(float4*)w_ = *(const float4*)&Ws[kk][tx * 4];
            #pragma unroll
            for (int i = 0; i < 4; ++i)
                #pragma unroll
                for (int j = 0; j < 4; ++j)
                    c[i][j] += a_[i] * w_[j];
        }
        __syncthreads();
    }

    float bv[4];
    *(float4*)bv = *(const float4*)(bias + n0 + tx * 4);
    #pragma unroll
    for (int i = 0; i < 4; ++i) {
        int row = m0 + ty * 4 + i;
        if (row >= M) continue;
        size_t off = (size_t)row * Nn + n0 + tx * 4;
        float o[4];
        #pragma unroll
        for (int j = 0; j < 4; ++j) o[j] = c[i][j] + bv[j];
        if (res) {
            float rv[4];
            *(float4*)rv = *(const float4*)(res + off);
            #pragma unroll
            for (int j = 0; j < 4; ++j) o[j] += rv[j];
        }
        *(float4*)(C + off) = *(float4*)o;
    }
}

// ---------------------------------------------------------------------------
// Weight conversion: W (KxNn, f32 row-major) -> Wt (Nn x pitch, f16, transposed)
// so MFMA B-fragments (8 contiguous k) are a single 16B load.
// ---------------------------------------------------------------------------
__global__ __launch_bounds__(256)
void wconv_kernel(const float* __restrict__ W, _Float16* __restrict__ Wt,
                  int K, int Nn, int pitch)
{
    int idx = blockIdx.x * 256 + threadIdx.x;
    if (idx >= K * Nn) return;
    int k = idx / Nn, n = idx - k * Nn;
    Wt[(size_t)n * pitch + k] = (_Float16)W[(size_t)k * Nn + n];
}

// ---------------------------------------------------------------------------
// Fused MFMA FFN: out = relu(X@W1 + b1) @ W2 + b2 + res.
// X: Mx256 f32.  W1t: [512][264] f16 (transposed, K=256 + pad 8).
// W2t: [256][520] f16 (transposed, K=512 + pad 8).
// 32-row tile, 256 threads = 4 waves, mfma_f32_16x16x32_f16, fp32 accum.
// Mid (32x512) kept as f16 in LDS between the two GEMMs.
//
// Fragment convention (m89-verified): for D = mfma(A,B,C) 16x16x32:
//   A[i][k]: i = lane&15, k = (lane>>4)*8 + j   (8 contiguous k per lane)
//   B[k][j]: j = lane&15, k = (lane>>4)*8 + j
//   D[i][j]: j = lane&15, i = (lane>>4)*4 + reg
// ---------------------------------------------------------------------------
#define XP 264   // Xs pitch (halves): 256+8  -> row stride 132 words, 2-way bank alias (free)
#define MP 520   // Mid pitch (halves): 512+8
#define W1P 264  // W1t pitch
#define W2P 520  // W2t pitch

__global__ __launch_bounds__(256)
void ffn_mfma_kernel(const float* __restrict__ X, const _Float16* __restrict__ W1t,
                     const float* __restrict__ b1, const _Float16* __restrict__ W2t,
                     const float* __restrict__ b2, const float* __restrict__ res,
                     float* __restrict__ out, int M)
{
    __shared__ _Float16 Xs[32 * XP];    // 16896 B
    __shared__ _Float16 Mid[32 * MP];   // 33280 B  (total 50176 B)
    const int t  = threadIdx.x;
    const int m0 = blockIdx.x * 32;
    const int w  = t >> 6;         // wave 0..3
    const int l  = t & 63;
    const int lr = l & 15;         // fragment row/col lane index
    const int lk = l >> 4;         // k-group 0..3

    // ---- stage X tile (32x256 f32) -> Xs (f16) ----
    {
        int r  = t >> 3;            // 0..31
        int c0 = (t & 7) * 32;      // 0,32,..,224
        const float* src = X + (size_t)(m0 + r) * 256 + c0;
        _Float16* dstp = &Xs[r * XP + c0];
        #pragma unroll
        for (int j = 0; j < 4; ++j) {
            float4 a = *(const float4*)(src + 8 * j);
            float4 b = *(const float4*)(src + 8 * j + 4);
            f16x8 hv;
            hv[0] = (_Float16)a.x; hv[1] = (_Float16)a.y;
            hv[2] = (_Float16)a.z; hv[3] = (_Float16)a.w;
            hv[4] = (_Float16)b.x; hv[5] = (_Float16)b.y;
            hv[6] = (_Float16)b.z; hv[7] = (_Float16)b.w;
            *(f16x8*)(dstp + 8 * j) = hv;
        }
    }
    __syncthreads();

    // ---- phase 1: Mid(32x512) = relu(X @ W1 + b1) ----
    // wave w: rows band..band+15, cols nbase..nbase+255  (16 n-frags, 8 k-steps)
    const int band  = (w & 1) * 16;
    const int nbase = (w >> 1) * 256;
    f32x4 acc[16];
    #pragma unroll
    for (int i = 0; i < 16; ++i) acc[i] = (f32x4){0.f, 0.f, 0.f, 0.f};

    const _Float16* xrow = &Xs[(band + lr) * XP + lk * 8];
    #pragma unroll
    for (int ks = 0; ks < 8; ++ks) {
        f16x8 af = *(const f16x8*)(xrow + ks * 32);
        const _Float16* wp = W1t + (size_t)(nbase + lr) * W1P + ks * 32 + lk * 8;
        #pragma unroll
        for (int nf = 0; nf < 16; ++nf) {
            f16x8 bf = *(const f16x8*)(wp + (size_t)nf * 16 * W1P);
            acc[nf] = __builtin_amdgcn_mfma_f32_16x16x32_f16(af, bf, acc[nf], 0, 0, 0);
        }
    }

    // bias + relu -> Mid (f16).  D row = band + lk*4 + r, col = nbase + nf*16 + lr
    #pragma unroll
    for (int nf = 0; nf < 16; ++nf) {
        int col = nbase + nf * 16 + lr;
        float bb = b1[col];
        #pragma unroll
        for (int r = 0; r < 4; ++r) {
            int row = band + lk * 4 + r;
            Mid[row * MP + col] = (_Float16)fmaxf(acc[nf][r] + bb, 0.f);
        }
    }
    __syncthreads();

    // ---- phase 2: out(32x256) = Mid @ W2 + b2 + res ----
    // wave w: rows band..band+15, cols cbase..cbase+127  (8 n-frags, 16 k-steps)
    const int cbase = (w >> 1) * 128;
    f32x4 acc2[8];
    #pragma unroll
    for (int i = 0; i < 8; ++i) acc2[i] = (f32x4){0.f, 0.f, 0.f, 0.f};

    const _Float16* mrow = &Mid[(band + lr) * MP + lk * 8];
    #pragma unroll
    for (int ks = 0; ks < 16; ++ks) {
        f16x8 af = *(const f16x8*)(mrow + ks * 32);
        const _Float16* wp = W2t + (size_t)(cbase + lr) * W2P + ks * 32 + lk * 8;
        #pragma unroll
        for (int nf = 0; nf < 8; ++nf) {
            f16x8 bf = *(const f16x8*)(wp + (size_t)nf * 16 * W2P);
            acc2[nf] = __builtin_amdgcn_mfma_f32_16x16x32_f16(af, bf, acc2[nf], 0, 0, 0);
        }
    }

    #pragma unroll
    for (int nf = 0; nf < 8; ++nf) {
        int col = cbase + nf * 16 + lr;
        float bb = b2[col];
        #pragma unroll
        for (int r = 0; r < 4; ++r) {
            int row = m0 + band + lk * 4 + r;
            size_t off = (size_t)row * 256 + col;
            out[off] = acc2[nf][r] + bb + res[off];
        }
    }
}

// ---------------------------------------------------------------------------
// Sparse-graph edge kernel. (unchanged)
// ---------------------------------------------------------------------------
__global__ __launch_bounds__(256)
void sedge_kernel(const float* __restrict__ Kh, const float* __restrict__ Qh,
                  const float* __restrict__ Vh, float* __restrict__ pe,
                  const int* __restrict__ src, const int* __restrict__ dst,
                  float* __restrict__ wV, float* __restrict__ z)
{
    const int e = blockIdx.x;
    const int t = threadIdx.x;
    const int s_ = src[e], d_ = dst[e];
    const size_t eb = (size_t)e * 256;
    float k = Kh[(size_t)s_ * 256 + t];
    float q = Qh[(size_t)d_ * 256 + t];
    float p = pe[eb + t];
    float score = k * q * INV_SCALE * p;
    pe[eb + t] = score;
    float red = score;
    red += __shfl_down(red, 16, 32);
    red += __shfl_down(red, 8, 32);
    red += __shfl_down(red, 4, 32);
    red += __shfl_down(red, 2, 32);
    red += __shfl_down(red, 1, 32);
    float ssum = __shfl(red, 0, 32);
    float sexp = expf(fminf(fmaxf(ssum, -5.f), 5.f));
    float v = Vh[(size_t)s_ * 256 + t];
    atomicAdd(&wV[(size_t)d_ * 256 + t], v * sexp);
    if ((t & 31) == 0) atomicAdd(&z[d_ * NHEAD + (t >> 5)], sexp);
}

// ---------------------------------------------------------------------------
// Full-graph edge kernel. (unchanged)
// ---------------------------------------------------------------------------
__global__ __launch_bounds__(256)
void fedge_kernel(const float* __restrict__ Kh, const float* __restrict__ Qh,
                  const float* __restrict__ Vh,
                  const int* __restrict__ fsrc, const int* __restrict__ fdst,
                  const float* __restrict__ adj2, const float* __restrict__ rel,
                  float* __restrict__ wVf, float* __restrict__ zf)
{
    const int e = blockIdx.x;
    const int t = threadIdx.x;
    const int h = t >> 5;
    const int s_ = fsrc[e], d_ = fdst[e];
    float prod = Kh[(size_t)s_ * 256 + t] * Qh[(size_t)d_ * 256 + t];
    float red = prod;
    red += __shfl_down(red, 16, 32);
    red += __shfl_down(red, 8, 32);
    red += __shfl_down(red, 4, 32);
    red += __shfl_down(red, 2, 32);
    red += __shfl_down(red, 1, 32);
    float sc = __shfl(red, 0, 32) * INV_SCALE;
    float sf = expf(fminf(fmaxf(sc + rel[(size_t)e * NHEAD + h], -5.f), 5.f) * adj2[e]);
    atomicAdd(&wVf[(size_t)d_ * 256 + t], Vh[(size_t)s_ * 256 + t] * sf);
    if ((t & 31) == 0) atomicAdd(&zf[d_ * NHEAD + h], sf);
}

// h_attn = wV/(z+eps) + wVf/(zf+eps)
__global__ __launch_bounds__(256)
void hattn_kernel(const float* __restrict__ wV, const float* __restrict__ z,
                  const float* __restrict__ wVf, const float* __restrict__ zf,
                  float* __restrict__ ha)
{
    size_t i = (size_t)blockIdx.x * 256 + threadIdx.x;
    int n = (int)(i >> 8);
    int h = (int)((i >> 5) & 7);
    ha[i] = wV[i] / (z[n * NHEAD + h] + 1e-6f) + wVf[i] / (zf[n * NHEAD + h] + 1e-6f);
}

// graph boundary detection on sorted graph_ids -> gstart[0..NG] (gstart[NG]=N)
__global__ void bounds_kernel(const int* __restrict__ gid, int* __restrict__ gstart,
                              int n_, int ng)
{
    int n = blockIdx.x * 256 + threadIdx.x;
    if (n >= n_) return;
    int cur = gid[n];
    int prev = (n == 0) ? -1 : gid[n - 1];
    for (int g = prev + 1; g <= cur; ++g) gstart[g] = n;
    if (n == n_ - 1)
        for (int g = cur + 1; g <= ng; ++g) gstart[g] = n_;
}

// GraphNorm in place: one block per graph, thread d = feature.
__global__ __launch_bounds__(256)
void gn_kernel(float* __restrict__ x, const float* __restrict__ alpha,
               const float* __restrict__ gamma, const float* __restrict__ beta,
               const int* __restrict__ gstart)
{
    const int g = blockIdx.x;
    const int d = threadIdx.x;
    const int s = gstart[g], en = gstart[g + 1];
    if (s >= en) return;
    const float cnt = (float)(en - s);
    float sum = 0.f;
    for (int n = s; n < en; ++n) sum += x[(size_t)n * 256 + d];
    const float mean = sum / cnt;
    const float am = alpha[d] * mean;
    float sum2 = 0.f;
    for (int n = s; n < en; ++n) {
        float v = x[(size_t)n * 256 + d] - am;
        sum2 += v * v;
    }
    const float inv = 1.0f / sqrtf(sum2 / cnt + 1e-6f);
    const float gm = gamma[d], bt = beta[d];
    for (int n = s; n < en; ++n) {
        float v = x[(size_t)n * 256 + d] - am;
        x[(size_t)n * 256 + d] = gm * v * inv + bt;
    }
}

// LayerNorm over D=256, in place. One 64-lane wave per row, 4 rows per block.
__global__ __launch_bounds__(256)
void ln_kernel(float* __restrict__ x, const float* __restrict__ g,
               const float* __restrict__ b, int M)
{
    int row = blockIdx.x * 4 + (threadIdx.x >> 6);
    int lane = threadIdx.x & 63;
    if (row >= M) return;
    float* xr = x + (size_t)row * 256;
    float v0 = xr[lane], v1 = xr[lane + 64], v2 = xr[lane + 128], v3 = xr[lane + 192];
    float s = v0 + v1 + v2 + v3;
    for (int off = 32; off; off >>= 1) s += __shfl_down(s, off, 64);
    float mu = __shfl(s, 0, 64) * (1.0f / 256.0f);
    float d0 = v0 - mu, d1 = v1 - mu, d2 = v2 - mu, d3 = v3 - mu;
    float q = d0 * d0 + d1 * d1 + d2 * d2 + d3 * d3;
    for (int off = 32; off; off >>= 1) q += __shfl_down(q, off, 64);
    float var = __shfl(q, 0, 64) * (1.0f / 256.0f);
    float inv = 1.0f / sqrtf(var + 1e-5f);
    xr[lane]       = d0 * inv * g[lane]       + b[lane];
    xr[lane + 64]  = d1 * inv * g[lane + 64]  + b[lane + 64];
    xr[lane + 128] = d2 * inv * g[lane + 128] + b[lane + 128];
    xr[lane + 192] = d3 * inv * g[lane + 192] + b[lane + 192];
}

// ---------------------------------------------------------------------------
extern "C" void kernel_launch(void* const* d_in, const int* in_sizes, int n_in,
                              void* d_out, int out_size, void* d_ws, size_t ws_size,
                              hipStream_t stream)
{
    const float* h        = (const float*)d_in[0];
    const float* e        = (const float*)d_in[1];
    const int*   src      = (const int*)d_in[2];
    const int*   dst      = (const int*)d_in[3];
    const int*   fsrc     = (const int*)d_in[4];
    const int*   fdst     = (const int*)d_in[5];
    const float* adj2     = (const float*)d_in[6];
    const float* rel      = (const float*)d_in[7];
    const int*   gids     = (const int*)d_in[8];
    const float* Qw  = (const float*)d_in[9];
    const float* Kw  = (const float*)d_in[10];
    const float* Vw  = (const float*)d_in[11];
    const float* Pw  = (const float*)d_in[12];
    const float* Ohw = (const float*)d_in[13];
    const float* Oew = (const float*)d_in[14];
    const float* Qb  = (const float*)d_in[15];
    const float* Kb  = (const float*)d_in[16];
    const float* Vb  = (const float*)d_in[17];
    const float* Pb  = (const float*)d_in[18];
    const float* Ohb = (const float*)d_in[19];
    const float* Oeb = (const float*)d_in[20];
    const float* f1hw = (const float*)d_in[21];
    const float* f1hb = (const float*)d_in[22];
    const float* f2hw = (const float*)d_in[23];
    const float* f2hb = (const float*)d_in[24];
    const float* f1ew = (const float*)d_in[25];
    const float* f1eb = (const float*)d_in[26];
    const float* f2ew = (const float*)d_in[27];
    const float* f2eb = (const float*)d_in[28];
    const float* gn1_alpha = (const float*)d_in[29];
    const float* gn1_gamma = (const float*)d_in[30];
    const float* gn2_alpha = (const float*)d_in[31];
    const float* gn2_gamma = (const float*)d_in[32];
    const float* ln1e_g = (const float*)d_in[33];
    const float* ln2e_g = (const float*)d_in[34];
    const float* gn1_beta = (const float*)d_in[35];
    const float* gn2_beta = (const float*)d_in[36];
    const float* ln1e_b = (const float*)d_in[37];
    const float* ln2e_b = (const float*)d_in[38];

    const size_t ND = (size_t)NNODE * DIM;   // 5,120,000
    const size_t ED = (size_t)NEDGE * DIM;   // 81,920,000

    float* wsf    = (float*)d_ws;
    float* Qh     = wsf;
    float* Kh     = Qh + ND;
    float* Vh     = Kh + ND;
    float* wV     = Vh + ND;
    float* wVf    = wV + ND;
    float* z      = wVf + ND;
    float* zf     = z + (size_t)NNODE * NHEAD;
    float* h_attn = zf + (size_t)NNODE * NHEAD;
    float* h2     = h_attn + ND;
    float* e2     = h2 + ND;
    int*   gstart = (int*)(e2 + ED);         // NGRAPH+1 ints

    // f16 transposed FFN weights, placed in the wV region which is dead after
    // hattn_kernel (conversions launch after the output-projection GEMMs).
    // Total: (512*264 + 256*520)*2 halves = 1.05 MB << 20.5 MB region.
    _Float16* w1h_t = (_Float16*)wV;
    _Float16* w2h_t = w1h_t + 512 * 264;
    _Float16* w1e_t = w2h_t + 256 * 520;
    _Float16* w2e_t = w1e_t + 512 * 264;

    float* out_h = (float*)d_out;            // final h2  [N,256]
    float* out_e = out_h + ND;               // proj_e -> e_out -> final e2 [E,256]

    // zero the scatter accumulators (wV, wVf, z, zf are contiguous)
    hipMemsetAsync(wV, 0, (2 * ND + 2 * (size_t)NNODE * NHEAD) * sizeof(float), stream);

    dim3 blk(256);
    // QKV projections
    gemm_kernel<<<dim3(4, 313), blk, 0, stream>>>(h, Qw, Qb, nullptr, Qh, NNODE, 256, 256);
    gemm_kernel<<<dim3(4, 313), blk, 0, stream>>>(h, Kw, Kb, nullptr, Kh, NNODE, 256, 256);
    gemm_kernel<<<dim3(4, 313), blk, 0, stream>>>(h, Vw, Vb, nullptr, Vh, NNODE, 256, 256);
    // proj_e into the e-output region (overwritten as e_out in sedge_kernel)
    gemm_kernel<<<dim3(4, 5000), blk, 0, stream>>>(e, Pw, Pb, nullptr, out_e, NEDGE, 256, 256);

    bounds_kernel<<<(NNODE + 255) / 256, blk, 0, stream>>>(gids, gstart, NNODE, NGRAPH);

    sedge_kernel<<<NEDGE, blk, 0, stream>>>(Kh, Qh, Vh, out_e, src, dst, wV, z);
    fedge_kernel<<<NFEDGE, blk, 0, stream>>>(Kh, Qh, Vh, fsrc, fdst, adj2, rel, wVf, zf);

    hattn_kernel<<<(int)(ND / 256), blk, 0, stream>>>(wV, z, wVf, zf, h_attn);

    // output projections with residual
    gemm_kernel<<<dim3(4, 313), blk, 0, stream>>>(h_attn, Ohw, Ohb, h, h2, NNODE, 256, 256);
    gemm_kernel<<<dim3(4, 5000), blk, 0, stream>>>(out_e, Oew, Oeb, e, e2, NEDGE, 256, 256);

    // convert FFN weights to f16 transposed (wV region is dead now)
    wconv_kernel<<<(256 * 512 + 255) / 256, blk, 0, stream>>>(f1hw, w1h_t, 256, 512, 264);
    wconv_kernel<<<(512 * 256 + 255) / 256, blk, 0, stream>>>(f2hw, w2h_t, 512, 256, 520);
    wconv_kernel<<<(256 * 512 + 255) / 256, blk, 0, stream>>>(f1ew, w1e_t, 256, 512, 264);
    wconv_kernel<<<(512 * 256 + 255) / 256, blk, 0, stream>>>(f2ew, w2e_t, 512, 256, 520);

    // norms (in place)
    gn_kernel<<<NGRAPH, blk, 0, stream>>>(h2, gn1_alpha, gn1_gamma, gn1_beta, gstart);
    ln_kernel<<<NEDGE / 4, blk, 0, stream>>>(e2, ln1e_g, ln1e_b, NEDGE);

    // fused MFMA FFNs (residual = normed input), write into d_out
    ffn_mfma_kernel<<<NNODE / 32, blk, 0, stream>>>(h2, w1h_t, f1hb, w2h_t, f2hb, h2, out_h, NNODE);
    ffn_mfma_kernel<<<NEDGE / 32, blk, 0, stream>>>(e2, w1e_t, f1eb, w2e_t, f2eb, e2, out_e, NEDGE);

    // final norms in place on d_out
    gn_kernel<<<NGRAPH, blk, 0, stream>>>(out_h, gn2_alpha, gn2_gamma, gn2_beta, gstart);
    ln_kernel<<<NEDGE / 4, blk, 0, stream>>>(out_e, ln2e_g, ln2e_b, NEDGE);
}

// Round 2
// 3373.980 us; speedup vs baseline: 1.9902x; 1.3726x over previous
//
#include <hip/hip_runtime.h>
#include <cstddef>
#include <cstdint>

#define NNODE 20000
#define NEDGE 320000
#define NFEDGE 500000
#define DIM 256
#define NHEAD 8
#define NGRAPH 100
// 1/sqrt(32)
#define INV_SCALE 0.17677669529663687f

typedef _Float16 f16x8 __attribute__((ext_vector_type(8)));
typedef float f32x4 __attribute__((ext_vector_type(4)));

// pitches (in halves): K + 8 pad
#define XP 264   // X tile pitch (K=256)
#define MP 520   // Mid tile pitch (K=512)
#define W1P 264  // W1t pitch (K=256)
#define W2P 520  // W2t pitch (K=512)
#define WQP 264  // square-weight pitch (K=256)

// ---------------------------------------------------------------------------
// Generic fp32 GEMM (kept for the small node projections).
// ---------------------------------------------------------------------------
__global__ __launch_bounds__(256)
void gemm_kernel(const float* __restrict__ A, const float* __restrict__ W,
                 const float* __restrict__ bias, const float* __restrict__ res,
                 float* __restrict__ C, int M, int K, int Nn)
{
    __shared__ float As[16][64];
    __shared__ float Ws[16][64];
    const int tid = threadIdx.x;
    const int tx = tid & 15;
    const int ty = tid >> 4;
    const int m0 = blockIdx.y * 64;
    const int n0 = blockIdx.x * 64;

    float c[4][4] = {};

    for (int k0 = 0; k0 < K; k0 += 16) {
        {
            int r  = tid >> 2;
            int k4 = (tid & 3) * 4;
            int row = m0 + r; if (row >= M) row = M - 1;
            const float4 v = *(const float4*)(A + (size_t)row * K + k0 + k4);
            As[k4 + 0][r] = v.x; As[k4 + 1][r] = v.y;
            As[k4 + 2][r] = v.z; As[k4 + 3][r] = v.w;
        }
        {
            int kr = tid >> 4;
            int n4 = (tid & 15) * 4;
            *(float4*)&Ws[kr][n4] = *(const float4*)(W + (size_t)(k0 + kr) * Nn + n0 + n4);
        }
        __syncthreads();
        #pragma unroll
        for (int kk = 0; kk < 16; ++kk) {
            float a_[4], w_[4];
            *(float4*)a_ = *(const float4*)&As[kk][ty * 4];
            *(float4*)w_ = *(const float4*)&Ws[kk][tx * 4];
            #pragma unroll
            for (int i = 0; i < 4; ++i)
                #pragma unroll
                for (int j = 0; j < 4; ++j)
                    c[i][j] += a_[i] * w_[j];
        }
        __syncthreads();
    }

    float bv[4];
    *(float4*)bv = *(const float4*)(bias + n0 + tx * 4);
    #pragma unroll
    for (int i = 0; i < 4; ++i) {
        int row = m0 + ty * 4 + i;
        if (row >= M) continue;
        size_t off = (size_t)row * Nn + n0 + tx * 4;
        float o[4];
        #pragma unroll
        for (int j = 0; j < 4; ++j) o[j] = c[i][j] + bv[j];
        if (res) {
            float rv[4];
            *(float4*)rv = *(const float4*)(res + off);
            #pragma unroll
            for (int j = 0; j < 4; ++j) o[j] += rv[j];
        }
        *(float4*)(C + off) = *(float4*)o;
    }
}

// ---------------------------------------------------------------------------
// Weight conversion: W (KxNn f32 row-major) -> Wt (Nn x pitch f16, transposed).
// ---------------------------------------------------------------------------
__global__ __launch_bounds__(256)
void wconv_kernel(const float* __restrict__ W, _Float16* __restrict__ Wt,
                  int K, int Nn, int pitch)
{
    int idx = blockIdx.x * 256 + threadIdx.x;
    if (idx >= K * Nn) return;
    int k = idx / Nn, n = idx - k * Nn;
    Wt[(size_t)n * pitch + k] = (_Float16)W[(size_t)k * Nn + n];
}

// ---------------------------------------------------------------------------
// stage helper: 32x256 f32 rows -> f16 LDS tile (pitch XP). 256 threads.
// ---------------------------------------------------------------------------
__device__ __forceinline__ void stage32(const float* __restrict__ src0,
                                        _Float16* __restrict__ Xs, int t)
{
    int r  = t >> 3;            // 0..31
    int c0 = (t & 7) * 32;      // 0..224
    const float* src = src0 + (size_t)r * 256 + c0;
    _Float16* dstp = &Xs[r * XP + c0];
    #pragma unroll
    for (int j = 0; j < 4; ++j) {
        float4 a = *(const float4*)(src + 8 * j);
        float4 b = *(const float4*)(src + 8 * j + 4);
        f16x8 hv;
        hv[0] = (_Float16)a.x; hv[1] = (_Float16)a.y;
        hv[2] = (_Float16)a.z; hv[3] = (_Float16)a.w;
        hv[4] = (_Float16)b.x; hv[5] = (_Float16)b.y;
        hv[6] = (_Float16)b.z; hv[7] = (_Float16)b.w;
        *(f16x8*)(dstp + 8 * j) = hv;
    }
}

// ---------------------------------------------------------------------------
// MFMA GEMM, M x 256 @ 256 x 256: C = A@W + b (+res).  M % 32 == 0.
// 32-row tile, 4 waves; wave w covers all 32 rows (2 rf) x 64 cols (4 cf)
// => every B fragment feeds 2 MFMAs; B loads batched 4-wide + next-k
// register double-buffer.
// ---------------------------------------------------------------------------
__global__ __launch_bounds__(256, 4)
void gemm_mfma_kernel(const float* __restrict__ A, const _Float16* __restrict__ Wt,
                      const float* __restrict__ bias, const float* __restrict__ res,
                      float* __restrict__ C, int M)
{
    __shared__ _Float16 Xs[32 * XP];   // 16896 B
    const int t  = threadIdx.x;
    const int m0 = blockIdx.x * 32;

    stage32(A + (size_t)m0 * 256, Xs, t);
    __syncthreads();

    const int w = t >> 6, l = t & 63, lr = l & 15, lk = l >> 4;

    f32x4 acc[2][4];
    #pragma unroll
    for (int i = 0; i < 2; ++i)
        #pragma unroll
        for (int j = 0; j < 4; ++j) acc[i][j] = (f32x4){0.f, 0.f, 0.f, 0.f};

    const _Float16* xb = &Xs[lr * XP + lk * 8];
    const _Float16* wb = Wt + (size_t)(w * 64 + lr) * WQP + lk * 8;

    f16x8 bf[4];
    #pragma unroll
    for (int cf = 0; cf < 4; ++cf) bf[cf] = *(const f16x8*)(wb + cf * 16 * WQP);

    #pragma unroll
    for (int ks = 0; ks < 8; ++ks) {
        f16x8 bn[4];
        if (ks < 7) {
            #pragma unroll
            for (int cf = 0; cf < 4; ++cf)
                bn[cf] = *(const f16x8*)(wb + (ks + 1) * 32 + cf * 16 * WQP);
        }
        f16x8 a0 = *(const f16x8*)(xb + ks * 32);
        f16x8 a1 = *(const f16x8*)(xb + 16 * XP + ks * 32);
        #pragma unroll
        for (int cf = 0; cf < 4; ++cf) {
            acc[0][cf] = __builtin_amdgcn_mfma_f32_16x16x32_f16(a0, bf[cf], acc[0][cf], 0, 0, 0);
            acc[1][cf] = __builtin_amdgcn_mfma_f32_16x16x32_f16(a1, bf[cf], acc[1][cf], 0, 0, 0);
        }
        if (ks < 7) {
            #pragma unroll
            for (int cf = 0; cf < 4; ++cf) bf[cf] = bn[cf];
        }
    }

    #pragma unroll
    for (int cf = 0; cf < 4; ++cf) {
        int col = w * 64 + cf * 16 + lr;
        float bb = bias[col];
        #pragma unroll
        for (int rf = 0; rf < 2; ++rf)
            #pragma unroll
            for (int r = 0; r < 4; ++r) {
                int row = m0 + rf * 16 + lk * 4 + r;
                size_t off = (size_t)row * 256 + col;
                float o = acc[rf][cf][r] + bb;
                if (res) o += res[off];
                C[off] = o;
            }
    }
}

// ---------------------------------------------------------------------------
// Fused MFMA FFN v2: out = relu(X@W1+b1)@W2 + b2 + res.  M % 32 == 0.
// Phase 1: wave w -> all 32 rows (2 rf) x 128 cols (8 cf), B reuse 2x,
//          8-wide batched B loads, next-k register double-buffer.
// Phase 2: wave w -> all 32 rows x 64 cols (4 cf), K=512.
// Mid (32x512 f16) in LDS between phases.
// ---------------------------------------------------------------------------
__global__ __launch_bounds__(256, 3)
void ffn_mfma_kernel(const float* __restrict__ X, const _Float16* __restrict__ W1t,
                     const float* __restrict__ b1, const _Float16* __restrict__ W2t,
                     const float* __restrict__ b2, const float* __restrict__ res,
                     float* __restrict__ out, int M)
{
    __shared__ _Float16 Xs[32 * XP];    // 16896 B
    __shared__ _Float16 Mid[32 * MP];   // 33280 B (total 50176 B -> 3 blk/CU)
    const int t  = threadIdx.x;
    const int m0 = blockIdx.x * 32;

    stage32(X + (size_t)m0 * 256, Xs, t);
    __syncthreads();

    const int w = t >> 6, l = t & 63, lr = l & 15, lk = l >> 4;

    // ---- phase 1 ----
    f32x4 acc[2][8];
    #pragma unroll
    for (int i = 0; i < 2; ++i)
        #pragma unroll
        for (int j = 0; j < 8; ++j) acc[i][j] = (f32x4){0.f, 0.f, 0.f, 0.f};

    const _Float16* xb  = &Xs[lr * XP + lk * 8];
    const _Float16* w1b = W1t + (size_t)(w * 128 + lr) * W1P + lk * 8;

    f16x8 bf[8];
    #pragma unroll
    for (int cf = 0; cf < 8; ++cf) bf[cf] = *(const f16x8*)(w1b + cf * 16 * W1P);

    #pragma unroll
    for (int ks = 0; ks < 8; ++ks) {
        f16x8 bn[8];
        if (ks < 7) {
            #pragma unroll
            for (int cf = 0; cf < 8; ++cf)
                bn[cf] = *(const f16x8*)(w1b + (ks + 1) * 32 + cf * 16 * W1P);
        }
        f16x8 a0 = *(const f16x8*)(xb + ks * 32);
        f16x8 a1 = *(const f16x8*)(xb + 16 * XP + ks * 32);
        #pragma unroll
        for (int cf = 0; cf < 8; ++cf) {
            acc[0][cf] = __builtin_amdgcn_mfma_f32_16x16x32_f16(a0, bf[cf], acc[0][cf], 0, 0, 0);
            acc[1][cf] = __builtin_amdgcn_mfma_f32_16x16x32_f16(a1, bf[cf], acc[1][cf], 0, 0, 0);
        }
        if (ks < 7) {
            #pragma unroll
            for (int cf = 0; cf < 8; ++cf) bf[cf] = bn[cf];
        }
    }

    // bias + relu -> Mid (f16)
    #pragma unroll
    for (int cf = 0; cf < 8; ++cf) {
        int col = w * 128 + cf * 16 + lr;
        float bb = b1[col];
        #pragma unroll
        for (int rf = 0; rf < 2; ++rf)
            #pragma unroll
            for (int r = 0; r < 4; ++r) {
                int row = rf * 16 + lk * 4 + r;
                Mid[row * MP + col] = (_Float16)fmaxf(acc[rf][cf][r] + bb, 0.f);
            }
    }
    __syncthreads();

    // ---- phase 2 ----
    f32x4 acc2[2][4];
    #pragma unroll
    for (int i = 0; i < 2; ++i)
        #pragma unroll
        for (int j = 0; j < 4; ++j) acc2[i][j] = (f32x4){0.f, 0.f, 0.f, 0.f};

    const _Float16* mb  = &Mid[lr * MP + lk * 8];
    const _Float16* w2b = W2t + (size_t)(w * 64 + lr) * W2P + lk * 8;

    f16x8 bf2[4];
    #pragma unroll
    for (int cf = 0; cf < 4; ++cf) bf2[cf] = *(const f16x8*)(w2b + cf * 16 * W2P);

    #pragma unroll
    for (int ks = 0; ks < 16; ++ks) {
        f16x8 bn2[4];
        if (ks < 15) {
            #pragma unroll
            for (int cf = 0; cf < 4; ++cf)
                bn2[cf] = *(const f16x8*)(w2b + (ks + 1) * 32 + cf * 16 * W2P);
        }
        f16x8 a0 = *(const f16x8*)(mb + ks * 32);
        f16x8 a1 = *(const f16x8*)(mb + 16 * MP + ks * 32);
        #pragma unroll
        for (int cf = 0; cf < 4; ++cf) {
            acc2[0][cf] = __builtin_amdgcn_mfma_f32_16x16x32_f16(a0, bf2[cf], acc2[0][cf], 0, 0, 0);
            acc2[1][cf] = __builtin_amdgcn_mfma_f32_16x16x32_f16(a1, bf2[cf], acc2[1][cf], 0, 0, 0);
        }
        if (ks < 15) {
            #pragma unroll
            for (int cf = 0; cf < 4; ++cf) bf2[cf] = bn2[cf];
        }
    }

    #pragma unroll
    for (int cf = 0; cf < 4; ++cf) {
        int col = w * 64 + cf * 16 + lr;
        float bb = b2[col];
        #pragma unroll
        for (int rf = 0; rf < 2; ++rf)
            #pragma unroll
            for (int r = 0; r < 4; ++r) {
                int row = m0 + rf * 16 + lk * 4 + r;
                size_t off = (size_t)row * 256 + col;
                out[off] = acc2[rf][cf][r] + bb + res[off];
            }
    }
}

// ---------------------------------------------------------------------------
// Sparse-graph edge kernel. (unchanged)
// ---------------------------------------------------------------------------
__global__ __launch_bounds__(256)
void sedge_kernel(const float* __restrict__ Kh, const float* __restrict__ Qh,
                  const float* __restrict__ Vh, float* __restrict__ pe,
                  const int* __restrict__ src, const int* __restrict__ dst,
                  float* __restrict__ wV, float* __restrict__ z)
{
    const int e = blockIdx.x;
    const int t = threadIdx.x;
    const int s_ = src[e], d_ = dst[e];
    const size_t eb = (size_t)e * 256;
    float k = Kh[(size_t)s_ * 256 + t];
    float q = Qh[(size_t)d_ * 256 + t];
    float p = pe[eb + t];
    float score = k * q * INV_SCALE * p;
    pe[eb + t] = score;
    float red = score;
    red += __shfl_down(red, 16, 32);
    red += __shfl_down(red, 8, 32);
    red += __shfl_down(red, 4, 32);
    red += __shfl_down(red, 2, 32);
    red += __shfl_down(red, 1, 32);
    float ssum = __shfl(red, 0, 32);
    float sexp = expf(fminf(fmaxf(ssum, -5.f), 5.f));
    float v = Vh[(size_t)s_ * 256 + t];
    atomicAdd(&wV[(size_t)d_ * 256 + t], v * sexp);
    if ((t & 31) == 0) atomicAdd(&z[d_ * NHEAD + (t >> 5)], sexp);
}

// ---------------------------------------------------------------------------
// Full-graph edge kernel. (unchanged)
// ---------------------------------------------------------------------------
__global__ __launch_bounds__(256)
void fedge_kernel(const float* __restrict__ Kh, const float* __restrict__ Qh,
                  const float* __restrict__ Vh,
                  const int* __restrict__ fsrc, const int* __restrict__ fdst,
                  const float* __restrict__ adj2, const float* __restrict__ rel,
                  float* __restrict__ wVf, float* __restrict__ zf)
{
    const int e = blockIdx.x;
    const int t = threadIdx.x;
    const int h = t >> 5;
    const int s_ = fsrc[e], d_ = fdst[e];
    float prod = Kh[(size_t)s_ * 256 + t] * Qh[(size_t)d_ * 256 + t];
    float red = prod;
    red += __shfl_down(red, 16, 32);
    red += __shfl_down(red, 8, 32);
    red += __shfl_down(red, 4, 32);
    red += __shfl_down(red, 2, 32);
    red += __shfl_down(red, 1, 32);
    float sc = __shfl(red, 0, 32) * INV_SCALE;
    float sf = expf(fminf(fmaxf(sc + rel[(size_t)e * NHEAD + h], -5.f), 5.f) * adj2[e]);
    atomicAdd(&wVf[(size_t)d_ * 256 + t], Vh[(size_t)s_ * 256 + t] * sf);
    if ((t & 31) == 0) atomicAdd(&zf[d_ * NHEAD + h], sf);
}

// h_attn = wV/(z+eps) + wVf/(zf+eps)
__global__ __launch_bounds__(256)
void hattn_kernel(const float* __restrict__ wV, const float* __restrict__ z,
                  const float* __restrict__ wVf, const float* __restrict__ zf,
                  float* __restrict__ ha)
{
    size_t i = (size_t)blockIdx.x * 256 + threadIdx.x;
    int n = (int)(i >> 8);
    int h = (int)((i >> 5) & 7);
    ha[i] = wV[i] / (z[n * NHEAD + h] + 1e-6f) + wVf[i] / (zf[n * NHEAD + h] + 1e-6f);
}

// graph boundary detection on sorted graph_ids -> gstart[0..NG]
__global__ void bounds_kernel(const int* __restrict__ gid, int* __restrict__ gstart,
                              int n_, int ng)
{
    int n = blockIdx.x * 256 + threadIdx.x;
    if (n >= n_) return;
    int cur = gid[n];
    int prev = (n == 0) ? -1 : gid[n - 1];
    for (int g = prev + 1; g <= cur; ++g) gstart[g] = n;
    if (n == n_ - 1)
        for (int g = cur + 1; g <= ng; ++g) gstart[g] = n_;
}

// GraphNorm in place: one block per graph, thread d = feature.
__global__ __launch_bounds__(256)
void gn_kernel(float* __restrict__ x, const float* __restrict__ alpha,
               const float* __restrict__ gamma, const float* __restrict__ beta,
               const int* __restrict__ gstart)
{
    const int g = blockIdx.x;
    const int d = threadIdx.x;
    const int s = gstart[g], en = gstart[g + 1];
    if (s >= en) return;
    const float cnt = (float)(en - s);
    float sum = 0.f;
    for (int n = s; n < en; ++n) sum += x[(size_t)n * 256 + d];
    const float mean = sum / cnt;
    const float am = alpha[d] * mean;
    float sum2 = 0.f;
    for (int n = s; n < en; ++n) {
        float v = x[(size_t)n * 256 + d] - am;
        sum2 += v * v;
    }
    const float inv = 1.0f / sqrtf(sum2 / cnt + 1e-6f);
    const float gm = gamma[d], bt = beta[d];
    for (int n = s; n < en; ++n) {
        float v = x[(size_t)n * 256 + d] - am;
        x[(size_t)n * 256 + d] = gm * v * inv + bt;
    }
}

// LayerNorm over D=256, in place. One 64-lane wave per row, 4 rows per block.
__global__ __launch_bounds__(256)
void ln_kernel(float* __restrict__ x, const float* __restrict__ g,
               const float* __restrict__ b, int M)
{
    int row = blockIdx.x * 4 + (threadIdx.x >> 6);
    int lane = threadIdx.x & 63;
    if (row >= M) return;
    float* xr = x + (size_t)row * 256;
    float v0 = xr[lane], v1 = xr[lane + 64], v2 = xr[lane + 128], v3 = xr[lane + 192];
    float s = v0 + v1 + v2 + v3;
    for (int off = 32; off; off >>= 1) s += __shfl_down(s, off, 64);
    float mu = __shfl(s, 0, 64) * (1.0f / 256.0f);
    float d0 = v0 - mu, d1 = v1 - mu, d2 = v2 - mu, d3 = v3 - mu;
    float q = d0 * d0 + d1 * d1 + d2 * d2 + d3 * d3;
    for (int off = 32; off; off >>= 1) q += __shfl_down(q, off, 64);
    float var = __shfl(q, 0, 64) * (1.0f / 256.0f);
    float inv = 1.0f / sqrtf(var + 1e-5f);
    xr[lane]       = d0 * inv * g[lane]       + b[lane];
    xr[lane + 64]  = d1 * inv * g[lane + 64]  + b[lane + 64];
    xr[lane + 128] = d2 * inv * g[lane + 128] + b[lane + 128];
    xr[lane + 192] = d3 * inv * g[lane + 192] + b[lane + 192];
}

// ---------------------------------------------------------------------------
extern "C" void kernel_launch(void* const* d_in, const int* in_sizes, int n_in,
                              void* d_out, int out_size, void* d_ws, size_t ws_size,
                              hipStream_t stream)
{
    const float* h        = (const float*)d_in[0];
    const float* e        = (const float*)d_in[1];
    const int*   src      = (const int*)d_in[2];
    const int*   dst      = (const int*)d_in[3];
    const int*   fsrc     = (const int*)d_in[4];
    const int*   fdst     = (const int*)d_in[5];
    const float* adj2     = (const float*)d_in[6];
    const float* rel      = (const float*)d_in[7];
    const int*   gids     = (const int*)d_in[8];
    const float* Qw  = (const float*)d_in[9];
    const float* Kw  = (const float*)d_in[10];
    const float* Vw  = (const float*)d_in[11];
    const float* Pw  = (const float*)d_in[12];
    const float* Ohw = (const float*)d_in[13];
    const float* Oew = (const float*)d_in[14];
    const float* Qb  = (const float*)d_in[15];
    const float* Kb  = (const float*)d_in[16];
    const float* Vb  = (const float*)d_in[17];
    const float* Pb  = (const float*)d_in[18];
    const float* Ohb = (const float*)d_in[19];
    const float* Oeb = (const float*)d_in[20];
    const float* f1hw = (const float*)d_in[21];
    const float* f1hb = (const float*)d_in[22];
    const float* f2hw = (const float*)d_in[23];
    const float* f2hb = (const float*)d_in[24];
    const float* f1ew = (const float*)d_in[25];
    const float* f1eb = (const float*)d_in[26];
    const float* f2ew = (const float*)d_in[27];
    const float* f2eb = (const float*)d_in[28];
    const float* gn1_alpha = (const float*)d_in[29];
    const float* gn1_gamma = (const float*)d_in[30];
    const float* gn2_alpha = (const float*)d_in[31];
    const float* gn2_gamma = (const float*)d_in[32];
    const float* ln1e_g = (const float*)d_in[33];
    const float* ln2e_g = (const float*)d_in[34];
    const float* gn1_beta = (const float*)d_in[35];
    const float* gn2_beta = (const float*)d_in[36];
    const float* ln1e_b = (const float*)d_in[37];
    const float* ln2e_b = (const float*)d_in[38];

    const size_t ND = (size_t)NNODE * DIM;   // 5,120,000
    const size_t ED = (size_t)NEDGE * DIM;   // 81,920,000

    float* wsf    = (float*)d_ws;
    float* Qh     = wsf;
    float* Kh     = Qh + ND;
    float* Vh     = Kh + ND;
    float* wV     = Vh + ND;
    float* wVf    = wV + ND;
    float* z      = wVf + ND;
    float* zf     = z + (size_t)NNODE * NHEAD;
    float* h_attn = zf + (size_t)NNODE * NHEAD;
    float* h2     = h_attn + ND;
    float* e2     = h2 + ND;
    int*   gstart = (int*)(e2 + ED);         // NGRAPH+1 ints

    float* out_h = (float*)d_out;            // final h2  [N,256]
    float* out_e = out_h + ND;               // proj_e -> e_out -> final e2 [E,256]

    // f16 transposed FFN weights in the wV region (dead after hattn_kernel;
    // conversions launch after the output-projection GEMMs).
    _Float16* w1h_t = (_Float16*)wV;
    _Float16* w2h_t = w1h_t + 512 * W1P;
    _Float16* w1e_t = w2h_t + 256 * W2P;
    _Float16* w2e_t = w1e_t + 512 * W1P;

    // f16 transposed Pw/Oew weights live in out_h (d_out), which is written
    // only by the node FFN at the very end (edge FFN is launched first).
    _Float16* wpT  = (_Float16*)out_h;        // 256*264 halves
    _Float16* woeT = wpT + 256 * WQP;         // 256*264 halves (total 270 KB << 20 MB)

    dim3 blk(256);

    // convert Pw / Oew up front (out_h region is dead until the node FFN)
    wconv_kernel<<<(256 * 256 + 255) / 256, blk, 0, stream>>>(Pw, wpT, 256, 256, WQP);
    wconv_kernel<<<(256 * 256 + 255) / 256, blk, 0, stream>>>(Oew, woeT, 256, 256, WQP);

    // zero the scatter accumulators (wV, wVf, z, zf are contiguous)
    hipMemsetAsync(wV, 0, (2 * ND + 2 * (size_t)NNODE * NHEAD) * sizeof(float), stream);

    // QKV projections (node, fp32)
    gemm_kernel<<<dim3(4, 313), blk, 0, stream>>>(h, Qw, Qb, nullptr, Qh, NNODE, 256, 256);
    gemm_kernel<<<dim3(4, 313), blk, 0, stream>>>(h, Kw, Kb, nullptr, Kh, NNODE, 256, 256);
    gemm_kernel<<<dim3(4, 313), blk, 0, stream>>>(h, Vw, Vb, nullptr, Vh, NNODE, 256, 256);
    // proj_e (edge, MFMA) into the e-output region
    gemm_mfma_kernel<<<NEDGE / 32, blk, 0, stream>>>(e, wpT, Pb, nullptr, out_e, NEDGE);

    bounds_kernel<<<(NNODE + 255) / 256, blk, 0, stream>>>(gids, gstart, NNODE, NGRAPH);

    sedge_kernel<<<NEDGE, blk, 0, stream>>>(Kh, Qh, Vh, out_e, src, dst, wV, z);
    fedge_kernel<<<NFEDGE, blk, 0, stream>>>(Kh, Qh, Vh, fsrc, fdst, adj2, rel, wVf, zf);

    hattn_kernel<<<(int)(ND / 256), blk, 0, stream>>>(wV, z, wVf, zf, h_attn);

    // output projections with residual
    gemm_kernel<<<dim3(4, 313), blk, 0, stream>>>(h_attn, Ohw, Ohb, h, h2, NNODE, 256, 256);
    gemm_mfma_kernel<<<NEDGE / 32, blk, 0, stream>>>(out_e, woeT, Oeb, e, e2, NEDGE);

    // convert FFN weights to f16 transposed (wV region is dead now)
    wconv_kernel<<<(256 * 512 + 255) / 256, blk, 0, stream>>>(f1hw, w1h_t, 256, 512, W1P);
    wconv_kernel<<<(512 * 256 + 255) / 256, blk, 0, stream>>>(f2hw, w2h_t, 512, 256, W2P);
    wconv_kernel<<<(256 * 512 + 255) / 256, blk, 0, stream>>>(f1ew, w1e_t, 256, 512, W1P);
    wconv_kernel<<<(512 * 256 + 255) / 256, blk, 0, stream>>>(f2ew, w2e_t, 512, 256, W2P);

    // norms (in place)
    gn_kernel<<<NGRAPH, blk, 0, stream>>>(h2, gn1_alpha, gn1_gamma, gn1_beta, gstart);
    ln_kernel<<<NEDGE / 4, blk, 0, stream>>>(e2, ln1e_g, ln1e_b, NEDGE);

    // fused MFMA FFNs. Edge FFN FIRST (node FFN overwrites out_h, which holds
    // the wpT/woeT scratch weights until here).
    ffn_mfma_kernel<<<NEDGE / 32, blk, 0, stream>>>(e2, w1e_t, f1eb, w2e_t, f2eb, e2, out_e, NEDGE);
    ffn_mfma_kernel<<<NNODE / 32, blk, 0, stream>>>(h2, w1h_t, f1hb, w2h_t, f2hb, h2, out_h, NNODE);

    // final norms in place on d_out
    gn_kernel<<<NGRAPH, blk, 0, stream>>>(out_h, gn2_alpha, gn2_gamma, gn2_beta, gstart);
    ln_kernel<<<NEDGE / 4, blk, 0, stream>>>(out_e, ln2e_g, ln2e_b, NEDGE);
}

// Round 4
// 2955.326 us; speedup vs baseline: 2.2721x; 1.1417x over previous
//
#include <hip/hip_runtime.h>
#include <cstddef>
#include <cstdint>

#define NNODE 20000
#define NEDGE 320000
#define NFEDGE 500000
#define DIM 256
#define NHEAD 8
#define NGRAPH 100
// 1/sqrt(32)
#define INV_SCALE 0.17677669529663687f

typedef _Float16 f16x8 __attribute__((ext_vector_type(8)));
typedef _Float16 f16x4 __attribute__((ext_vector_type(4)));
typedef float f32x4 __attribute__((ext_vector_type(4)));

#define MFMA16(a, b, c) __builtin_amdgcn_mfma_f32_16x16x32_f16(a, b, c, 0, 0, 0)

// ---------------------------------------------------------------------------
// Weight conversion: W (KxNn f32 row-major) -> Wt (Nn rows x K f16, transposed,
// pitch exactly K so 8-k fragments are contiguous 16B).
// ---------------------------------------------------------------------------
__global__ __launch_bounds__(256)
void wconv_kernel(const float* __restrict__ W, _Float16* __restrict__ Wt,
                  int K, int Nn)
{
    int idx = blockIdx.x * 256 + threadIdx.x;
    if (idx >= K * Nn) return;
    int k = idx / Nn, n = idx - k * Nn;
    Wt[(size_t)n * K + k] = (_Float16)W[(size_t)k * Nn + n];
}

// ---------------------------------------------------------------------------
// mm256: C[M x 256] = A[M x K] @ Wt^T + bias (+res | relu->f16).
//   Wt: [256 cols][K] f16.  K = NS*32 (NS = 8 or 16).
//   A: f32 (A16M=0) or f16 pitch K (A16M=1).
//   O16M=0: out32[M][256] = C + bias (+ res).
//   O16M=1: out16[row*opitch + ocol + col] = relu(C + bias) as f16.
//
// Block: 64 rows x 256 cols, 512 threads = 8 waves (2 row-groups x 4 col-groups).
// Both A and B staged per-32k slice into double-buffered LDS with plain
// load->ds_write staging; ONE __syncthreads per slice; next-slice global loads
// issued BEFORE the MFMA phase (issue-early / write-late), compiler-managed
// waitcnts throughout.  NO global_load_lds / inline asm / swizzles (round-3
// failure post-mortem: those mechanisms un-ablatable; rebuilt conservative).
// Epilogue: acc -> LDS (two 32-row halves) -> fully coalesced writes.
// LDS: As 2x5120B + Bs 2x16384B = 43008B; Cs f32[32][256]=32768B union'd.
// ---------------------------------------------------------------------------
template<int NS, int A16M, int O16M>
__global__ __launch_bounds__(512, 4)
void mm256(const float* __restrict__ A32, const _Float16* __restrict__ A16,
           const _Float16* __restrict__ Wt, const float* __restrict__ bias,
           const float* __restrict__ res, float* __restrict__ out32,
           _Float16* __restrict__ out16, int opitch, int ocol, int M)
{
    constexpr int K = NS * 32;
    __shared__ __align__(16) unsigned char lds[43008];
    _Float16* As = (_Float16*)lds;               // [2][64*40] (pitch 40 halves)
    _Float16* Bs = (_Float16*)(lds + 10240);     // [2][256*32]
    float*    Cs = (float*)lds;                  // [32][256] epilogue union

    const int t  = threadIdx.x;
    const int m0 = blockIdx.x * 64;
    const int w  = t >> 6, l = t & 63, lr = l & 15, lk = l >> 4;
    const int cg = w & 3, rg = w >> 2;

    // per-thread staging coordinates
    const int ar = t >> 3, ak = (t & 7) * 4;     // A: row 0..63, k-quad 0..28
    int arow = m0 + ar; if (arow >= M) arow = M - 1;
    const int bc = t >> 1, bk = (t & 1) * 16;    // B: col 0..255, k-half 0/16
    const _Float16* bsrc = Wt + (size_t)bc * K + bk;

    f32x4 acc[2][4];
    #pragma unroll
    for (int i = 0; i < 2; ++i)
        #pragma unroll
        for (int j = 0; j < 4; ++j) acc[i][j] = (f32x4){0.f, 0.f, 0.f, 0.f};

    // ---- prologue: stage slice 0 directly ----
    {
        if (A16M) {
            f16x4 v = *(const f16x4*)(A16 + (size_t)arow * K + ak);
            *(f16x4*)(As + ar * 40 + ak) = v;
        } else {
            float4 v = *(const float4*)(A32 + (size_t)arow * K + ak);
            f16x4 hv;
            hv[0] = (_Float16)v.x; hv[1] = (_Float16)v.y;
            hv[2] = (_Float16)v.z; hv[3] = (_Float16)v.w;
            *(f16x4*)(As + ar * 40 + ak) = hv;
        }
        f16x8 b0 = *(const f16x8*)(bsrc);
        f16x8 b1 = *(const f16x8*)(bsrc + 8);
        *(f16x8*)(Bs + bc * 32 + bk) = b0;
        *(f16x8*)(Bs + bc * 32 + bk + 8) = b1;
    }
    __syncthreads();

    // ---- main loop: one barrier per 32-k slice ----
    for (int s = 0; s < NS; ++s) {
        const int cur = s & 1, nxt = cur ^ 1;

        // issue next-slice global loads early (land after MFMAs, before writes)
        f16x4 av;
        f16x8 bv0, bv1;
        if (s + 1 < NS) {
            const int kg = (s + 1) * 32;
            if (A16M) {
                av = *(const f16x4*)(A16 + (size_t)arow * K + kg + ak);
            } else {
                float4 v = *(const float4*)(A32 + (size_t)arow * K + kg + ak);
                av[0] = (_Float16)v.x; av[1] = (_Float16)v.y;
                av[2] = (_Float16)v.z; av[3] = (_Float16)v.w;
            }
            bv0 = *(const f16x8*)(bsrc + kg);
            bv1 = *(const f16x8*)(bsrc + kg + 8);
        }

        // compute slice s from buf[cur]
        const _Float16* ap = As + cur * 2560 + (rg * 32 + lr) * 40 + lk * 8;
        f16x8 a0 = *(const f16x8*)(ap);
        f16x8 a1 = *(const f16x8*)(ap + 16 * 40);
        const _Float16* bp = Bs + cur * 8192 + (cg * 64 + lr) * 32 + lk * 8;
        f16x8 b0 = *(const f16x8*)(bp);
        f16x8 b1 = *(const f16x8*)(bp + 512);
        f16x8 b2 = *(const f16x8*)(bp + 1024);
        f16x8 b3 = *(const f16x8*)(bp + 1536);
        acc[0][0] = MFMA16(a0, b0, acc[0][0]);
        acc[1][0] = MFMA16(a1, b0, acc[1][0]);
        acc[0][1] = MFMA16(a0, b1, acc[0][1]);
        acc[1][1] = MFMA16(a1, b1, acc[1][1]);
        acc[0][2] = MFMA16(a0, b2, acc[0][2]);
        acc[1][2] = MFMA16(a1, b2, acc[1][2]);
        acc[0][3] = MFMA16(a0, b3, acc[0][3]);
        acc[1][3] = MFMA16(a1, b3, acc[1][3]);

        // write next slice into buf[nxt] (safe: its last readers finished
        // before the barrier at the end of iteration s-1)
        if (s + 1 < NS) {
            *(f16x4*)(As + nxt * 2560 + ar * 40 + ak) = av;
            *(f16x8*)(Bs + nxt * 8192 + bc * 32 + bk) = bv0;
            *(f16x8*)(Bs + nxt * 8192 + bc * 32 + bk + 8) = bv1;
        }
        __syncthreads();
    }

    // ---- epilogue: two 32-row halves through LDS, coalesced stores ----
    #pragma unroll
    for (int hh = 0; hh < 2; ++hh) {
        __syncthreads();
        if (rg == hh) {
            #pragma unroll
            for (int cf = 0; cf < 4; ++cf)
                #pragma unroll
                for (int rf = 0; rf < 2; ++rf)
                    #pragma unroll
                    for (int r = 0; r < 4; ++r)
                        Cs[(rf * 16 + lk * 4 + r) * 256 + cg * 64 + cf * 16 + lr]
                            = acc[rf][cf][r];
        }
        __syncthreads();
        const int r2 = t >> 4;
        const int row2 = m0 + hh * 32 + r2;
        if (row2 < M) {
            if (O16M) {
                _Float16* op = out16 + (size_t)row2 * opitch + ocol;
                const int cb = (t & 15) * 8;
                #pragma unroll
                for (int q = 0; q < 2; ++q) {
                    int col = cb + q * 128;
                    float4 v0 = *(const float4*)&Cs[r2 * 256 + col];
                    float4 v1 = *(const float4*)&Cs[r2 * 256 + col + 4];
                    float4 bb0 = *(const float4*)(bias + col);
                    float4 bb1 = *(const float4*)(bias + col + 4);
                    f16x8 hv;
                    hv[0] = (_Float16)fmaxf(v0.x + bb0.x, 0.f);
                    hv[1] = (_Float16)fmaxf(v0.y + bb0.y, 0.f);
                    hv[2] = (_Float16)fmaxf(v0.z + bb0.z, 0.f);
                    hv[3] = (_Float16)fmaxf(v0.w + bb0.w, 0.f);
                    hv[4] = (_Float16)fmaxf(v1.x + bb1.x, 0.f);
                    hv[5] = (_Float16)fmaxf(v1.y + bb1.y, 0.f);
                    hv[6] = (_Float16)fmaxf(v1.z + bb1.z, 0.f);
                    hv[7] = (_Float16)fmaxf(v1.w + bb1.w, 0.f);
                    *(f16x8*)(op + col) = hv;
                }
            } else {
                float* op = out32 + (size_t)row2 * 256;
                const float* rp = res ? res + (size_t)row2 * 256 : nullptr;
                const int cb = (t & 15) * 4;
                #pragma unroll
                for (int q = 0; q < 4; ++q) {
                    int col = cb + q * 64;
                    float4 v = *(const float4*)&Cs[r2 * 256 + col];
                    float4 bb = *(const float4*)(bias + col);
                    float4 o;
                    o.x = v.x + bb.x; o.y = v.y + bb.y;
                    o.z = v.z + bb.z; o.w = v.w + bb.w;
                    if (rp) {
                        float4 rv = *(const float4*)(rp + col);
                        o.x += rv.x; o.y += rv.y; o.z += rv.z; o.w += rv.w;
                    }
                    *(float4*)(op + col) = o;
                }
            }
        }
    }
}

// ---------------------------------------------------------------------------
// Sparse-graph edge kernel. (unchanged)
// ---------------------------------------------------------------------------
__global__ __launch_bounds__(256)
void sedge_kernel(const float* __restrict__ Kh, const float* __restrict__ Qh,
                  const float* __restrict__ Vh, float* __restrict__ pe,
                  const int* __restrict__ src, const int* __restrict__ dst,
                  float* __restrict__ wV, float* __restrict__ z)
{
    const int e = blockIdx.x;
    const int t = threadIdx.x;
    const int s_ = src[e], d_ = dst[e];
    const size_t eb = (size_t)e * 256;
    float k = Kh[(size_t)s_ * 256 + t];
    float q = Qh[(size_t)d_ * 256 + t];
    float p = pe[eb + t];
    float score = k * q * INV_SCALE * p;
    pe[eb + t] = score;
    float red = score;
    red += __shfl_down(red, 16, 32);
    red += __shfl_down(red, 8, 32);
    red += __shfl_down(red, 4, 32);
    red += __shfl_down(red, 2, 32);
    red += __shfl_down(red, 1, 32);
    float ssum = __shfl(red, 0, 32);
    float sexp = expf(fminf(fmaxf(ssum, -5.f), 5.f));
    float v = Vh[(size_t)s_ * 256 + t];
    atomicAdd(&wV[(size_t)d_ * 256 + t], v * sexp);
    if ((t & 31) == 0) atomicAdd(&z[d_ * NHEAD + (t >> 5)], sexp);
}

// ---------------------------------------------------------------------------
// Full-graph edge kernel. (unchanged)
// ---------------------------------------------------------------------------
__global__ __launch_bounds__(256)
void fedge_kernel(const float* __restrict__ Kh, const float* __restrict__ Qh,
                  const float* __restrict__ Vh,
                  const int* __restrict__ fsrc, const int* __restrict__ fdst,
                  const float* __restrict__ adj2, const float* __restrict__ rel,
                  float* __restrict__ wVf, float* __restrict__ zf)
{
    const int e = blockIdx.x;
    const int t = threadIdx.x;
    const int h = t >> 5;
    const int s_ = fsrc[e], d_ = fdst[e];
    float prod = Kh[(size_t)s_ * 256 + t] * Qh[(size_t)d_ * 256 + t];
    float red = prod;
    red += __shfl_down(red, 16, 32);
    red += __shfl_down(red, 8, 32);
    red += __shfl_down(red, 4, 32);
    red += __shfl_down(red, 2, 32);
    red += __shfl_down(red, 1, 32);
    float sc = __shfl(red, 0, 32) * INV_SCALE;
    float sf = expf(fminf(fmaxf(sc + rel[(size_t)e * NHEAD + h], -5.f), 5.f) * adj2[e]);
    atomicAdd(&wVf[(size_t)d_ * 256 + t], Vh[(size_t)s_ * 256 + t] * sf);
    if ((t & 31) == 0) atomicAdd(&zf[d_ * NHEAD + h], sf);
}

// h_attn = wV/(z+eps) + wVf/(zf+eps)
__global__ __launch_bounds__(256)
void hattn_kernel(const float* __restrict__ wV, const float* __restrict__ z,
                  const float* __restrict__ wVf, const float* __restrict__ zf,
                  float* __restrict__ ha)
{
    size_t i = (size_t)blockIdx.x * 256 + threadIdx.x;
    int n = (int)(i >> 8);
    int h = (int)((i >> 5) & 7);
    ha[i] = wV[i] / (z[n * NHEAD + h] + 1e-6f) + wVf[i] / (zf[n * NHEAD + h] + 1e-6f);
}

// graph boundary detection on sorted graph_ids -> gstart[0..NG]
__global__ void bounds_kernel(const int* __restrict__ gid, int* __restrict__ gstart,
                              int n_, int ng)
{
    int n = blockIdx.x * 256 + threadIdx.x;
    if (n >= n_) return;
    int cur = gid[n];
    int prev = (n == 0) ? -1 : gid[n - 1];
    for (int g = prev + 1; g <= cur; ++g) gstart[g] = n;
    if (n == n_ - 1)
        for (int g = cur + 1; g <= ng; ++g) gstart[g] = n_;
}

// GraphNorm in place: one block per graph, thread d = feature.
__global__ __launch_bounds__(256)
void gn_kernel(float* __restrict__ x, const float* __restrict__ alpha,
               const float* __restrict__ gamma, const float* __restrict__ beta,
               const int* __restrict__ gstart)
{
    const int g = blockIdx.x;
    const int d = threadIdx.x;
    const int s = gstart[g], en = gstart[g + 1];
    if (s >= en) return;
    const float cnt = (float)(en - s);
    float sum = 0.f;
    for (int n = s; n < en; ++n) sum += x[(size_t)n * 256 + d];
    const float mean = sum / cnt;
    const float am = alpha[d] * mean;
    float sum2 = 0.f;
    for (int n = s; n < en; ++n) {
        float v = x[(size_t)n * 256 + d] - am;
        sum2 += v * v;
    }
    const float inv = 1.0f / sqrtf(sum2 / cnt + 1e-6f);
    const float gm = gamma[d], bt = beta[d];
    for (int n = s; n < en; ++n) {
        float v = x[(size_t)n * 256 + d] - am;
        x[(size_t)n * 256 + d] = gm * v * inv + bt;
    }
}

// LayerNorm over D=256, in place. One 64-lane wave per row, 4 rows per block.
__global__ __launch_bounds__(256)
void ln_kernel(float* __restrict__ x, const float* __restrict__ g,
               const float* __restrict__ b, int M)
{
    int row = blockIdx.x * 4 + (threadIdx.x >> 6);
    int lane = threadIdx.x & 63;
    if (row >= M) return;
    float* xr = x + (size_t)row * 256;
    float v0 = xr[lane], v1 = xr[lane + 64], v2 = xr[lane + 128], v3 = xr[lane + 192];
    float s = v0 + v1 + v2 + v3;
    for (int off = 32; off; off >>= 1) s += __shfl_down(s, off, 64);
    float mu = __shfl(s, 0, 64) * (1.0f / 256.0f);
    float d0 = v0 - mu, d1 = v1 - mu, d2 = v2 - mu, d3 = v3 - mu;
    float q = d0 * d0 + d1 * d1 + d2 * d2 + d3 * d3;
    for (int off = 32; off; off >>= 1) q += __shfl_down(q, off, 64);
    float var = __shfl(q, 0, 64) * (1.0f / 256.0f);
    float inv = 1.0f / sqrtf(var + 1e-5f);
    xr[lane]       = d0 * inv * g[lane]       + b[lane];
    xr[lane + 64]  = d1 * inv * g[lane + 64]  + b[lane + 64];
    xr[lane + 128] = d2 * inv * g[lane + 128] + b[lane + 128];
    xr[lane + 192] = d3 * inv * g[lane + 192] + b[lane + 192];
}

// ---------------------------------------------------------------------------
extern "C" void kernel_launch(void* const* d_in, const int* in_sizes, int n_in,
                              void* d_out, int out_size, void* d_ws, size_t ws_size,
                              hipStream_t stream)
{
    const float* h        = (const float*)d_in[0];
    const float* e        = (const float*)d_in[1];
    const int*   src      = (const int*)d_in[2];
    const int*   dst      = (const int*)d_in[3];
    const int*   fsrc     = (const int*)d_in[4];
    const int*   fdst     = (const int*)d_in[5];
    const float* adj2     = (const float*)d_in[6];
    const float* rel      = (const float*)d_in[7];
    const int*   gids     = (const int*)d_in[8];
    const float* Qw  = (const float*)d_in[9];
    const float* Kw  = (const float*)d_in[10];
    const float* Vw  = (const float*)d_in[11];
    const float* Pw  = (const float*)d_in[12];
    const float* Ohw = (const float*)d_in[13];
    const float* Oew = (const float*)d_in[14];
    const float* Qb  = (const float*)d_in[15];
    const float* Kb  = (const float*)d_in[16];
    const float* Vb  = (const float*)d_in[17];
    const float* Pb  = (const float*)d_in[18];
    const float* Ohb = (const float*)d_in[19];
    const float* Oeb = (const float*)d_in[20];
    const float* f1hw = (const float*)d_in[21];
    const float* f1hb = (const float*)d_in[22];
    const float* f2hw = (const float*)d_in[23];
    const float* f2hb = (const float*)d_in[24];
    const float* f1ew = (const float*)d_in[25];
    const float* f1eb = (const float*)d_in[26];
    const float* f2ew = (const float*)d_in[27];
    const float* f2eb = (const float*)d_in[28];
    const float* gn1_alpha = (const float*)d_in[29];
    const float* gn1_gamma = (const float*)d_in[30];
    const float* gn2_alpha = (const float*)d_in[31];
    const float* gn2_gamma = (const float*)d_in[32];
    const float* ln1e_g = (const float*)d_in[33];
    const float* ln2e_g = (const float*)d_in[34];
    const float* gn1_beta = (const float*)d_in[35];
    const float* gn2_beta = (const float*)d_in[36];
    const float* ln1e_b = (const float*)d_in[37];
    const float* ln2e_b = (const float*)d_in[38];

    const size_t ND = (size_t)NNODE * DIM;   // 5,120,000
    const size_t ED = (size_t)NEDGE * DIM;   // 81,920,000

    float* wsf    = (float*)d_ws;
    float* Qh     = wsf;
    float* Kh     = Qh + ND;
    float* Vh     = Kh + ND;
    float* wV     = Vh + ND;
    float* wVf    = wV + ND;
    float* z      = wVf + ND;
    float* zf     = z + (size_t)NNODE * NHEAD;
    float* h_attn = zf + (size_t)NNODE * NHEAD;
    float* h2     = h_attn + ND;
    float* e2     = h2 + ND;
    int*   gstart = (int*)(e2 + ED);         // NGRAPH+1 ints

    float* out_h = (float*)d_out;            // final h2  [N,256]
    float* out_e = out_h + ND;               // proj_e -> e_out -> final e2 [E,256]

    // Early f16 weights live in out_h (d_out), dead until node-FFN pass 3
    // (which runs last among GEMMs). 1.18 MB << 20.5 MB.
    _Float16* wearly = (_Float16*)out_h;
    _Float16* wqT  = wearly;                  // 256x256
    _Float16* wkT  = wearly + 65536;
    _Float16* wvT  = wearly + 131072;
    _Float16* wpT  = wearly + 196608;
    _Float16* woeT = wearly + 262144;
    _Float16* w1eT = wearly + 327680;         // 512 cols x 256
    _Float16* w2eT = wearly + 458752;         // 256 cols x 512   (end 589824)

    // Late weights + FFN Mid chunks live in Qh.. (dead after fedge).
    _Float16* wlate = (_Float16*)Qh;
    _Float16* wohT = wlate;                   // 256x256
    _Float16* w1hT = wlate + 65536;           // 512x256
    _Float16* w2hT = wlate + 196608;          // 256x512  (end 327680)
    _Float16* MidE = wlate + 327680;          // 80000x512 halves (ends 0.66MB into dead wVf)
    _Float16* MidH = (_Float16*)wV;           // 20000x512 halves

    dim3 b256(256), b512(512);

    // early weight conversions
    wconv_kernel<<<256, b256, 0, stream>>>(Qw,  wqT,  256, 256);
    wconv_kernel<<<256, b256, 0, stream>>>(Kw,  wkT,  256, 256);
    wconv_kernel<<<256, b256, 0, stream>>>(Vw,  wvT,  256, 256);
    wconv_kernel<<<256, b256, 0, stream>>>(Pw,  wpT,  256, 256);
    wconv_kernel<<<256, b256, 0, stream>>>(Oew, woeT, 256, 256);
    wconv_kernel<<<512, b256, 0, stream>>>(f1ew, w1eT, 256, 512);
    wconv_kernel<<<512, b256, 0, stream>>>(f2ew, w2eT, 512, 256);

    // zero the scatter accumulators (wV, wVf, z, zf are contiguous)
    hipMemsetAsync(wV, 0, (2 * ND + 2 * (size_t)NNODE * NHEAD) * sizeof(float), stream);

    // QKV projections + proj_e (all MFMA)
    mm256<8, 0, 0><<<313, b512, 0, stream>>>(h, nullptr, wqT, Qb, nullptr, Qh, nullptr, 0, 0, NNODE);
    mm256<8, 0, 0><<<313, b512, 0, stream>>>(h, nullptr, wkT, Kb, nullptr, Kh, nullptr, 0, 0, NNODE);
    mm256<8, 0, 0><<<313, b512, 0, stream>>>(h, nullptr, wvT, Vb, nullptr, Vh, nullptr, 0, 0, NNODE);
    mm256<8, 0, 0><<<5000, b512, 0, stream>>>(e, nullptr, wpT, Pb, nullptr, out_e, nullptr, 0, 0, NEDGE);

    bounds_kernel<<<(NNODE + 255) / 256, b256, 0, stream>>>(gids, gstart, NNODE, NGRAPH);

    sedge_kernel<<<NEDGE, b256, 0, stream>>>(Kh, Qh, Vh, out_e, src, dst, wV, z);
    fedge_kernel<<<NFEDGE, b256, 0, stream>>>(Kh, Qh, Vh, fsrc, fdst, adj2, rel, wVf, zf);

    // late weight conversions (Qh region dead now)
    wconv_kernel<<<256, b256, 0, stream>>>(Ohw,  wohT, 256, 256);
    wconv_kernel<<<512, b256, 0, stream>>>(f1hw, w1hT, 256, 512);
    wconv_kernel<<<512, b256, 0, stream>>>(f2hw, w2hT, 512, 256);

    hattn_kernel<<<(int)(ND / 256), b256, 0, stream>>>(wV, z, wVf, zf, h_attn);

    // output projections with residual
    mm256<8, 0, 0><<<313, b512, 0, stream>>>(h_attn, nullptr, wohT, Ohb, h, h2, nullptr, 0, 0, NNODE);
    mm256<8, 0, 0><<<5000, b512, 0, stream>>>(out_e, nullptr, woeT, Oeb, e, e2, nullptr, 0, 0, NEDGE);

    // norms (in place)
    gn_kernel<<<NGRAPH, b256, 0, stream>>>(h2, gn1_alpha, gn1_gamma, gn1_beta, gstart);
    ln_kernel<<<NEDGE / 4, b256, 0, stream>>>(e2, ln1e_g, ln1e_b, NEDGE);

    // edge FFN: 4 chunks of 80000 rows, 3 passes each (Mid f16 in workspace)
    for (int c = 0; c < 4; ++c) {
        const float* Xc = e2 + (size_t)c * 80000 * 256;
        float*       Oc = out_e + (size_t)c * 80000 * 256;
        mm256<8, 0, 1><<<1250, b512, 0, stream>>>(Xc, nullptr, w1eT, f1eb, nullptr,
                                                  nullptr, MidE, 512, 0, 80000);
        mm256<8, 0, 1><<<1250, b512, 0, stream>>>(Xc, nullptr, w1eT + 65536, f1eb + 256,
                                                  nullptr, nullptr, MidE, 512, 256, 80000);
        mm256<16, 1, 0><<<1250, b512, 0, stream>>>(nullptr, MidE, w2eT, f2eb, Xc,
                                                   Oc, nullptr, 0, 0, 80000);
    }

    // node FFN (overwrites out_h -> early weights dead; runs after edge FFN)
    mm256<8, 0, 1><<<313, b512, 0, stream>>>(h2, nullptr, w1hT, f1hb, nullptr,
                                             nullptr, MidH, 512, 0, NNODE);
    mm256<8, 0, 1><<<313, b512, 0, stream>>>(h2, nullptr, w1hT + 65536, f1hb + 256,
                                             nullptr, nullptr, MidH, 512, 256, NNODE);
    mm256<16, 1, 0><<<313, b512, 0, stream>>>(nullptr, MidH, w2hT, f2hb, h2,
                                              out_h, nullptr, 0, 0, NNODE);

    // final norms in place on d_out
    gn_kernel<<<NGRAPH, b256, 0, stream>>>(out_h, gn2_alpha, gn2_gamma, gn2_beta, gstart);
    ln_kernel<<<NEDGE / 4, b256, 0, stream>>>(out_e, ln2e_g, ln2e_b, NEDGE);
}